// Round 9
// baseline (788.520 us; speedup 1.0000x reference)
//
#include <hip/hip_runtime.h>
#include <hip/hip_bf16.h>
#include <math.h>

// RWKV-7 Tmix forward, MI355X/gfx950.
// B=2 T=1024 C=2048 H=32 N=64. Outputs: xo [B,T,C], x[:,-1] [B,C], S_final [B,H,N,N].
// R15: rec store de-entanglement — per-step strided store (vmcnt-ordered with loads,
//      retire ~300cy, common to R8/R9/R10/R14 all pinned at 478cy/step) replaced by
//      register banking: lane kq==s keeps step tb+s's op (allreduce -> all lanes have it),
//      ONE 64-lane store per 16-step window (16x fewer vmcnt store entries).
//      Also: 7 tp_pack dispatches -> 1 tp_pack7; lastx folded into shift.

#define B_ 2
#define T_ 1024
#define C_ 2048
#define H_ 32
#define BT_ (B_*T_)
#define BTC_ ((size_t)BT_*C_)
#define CC_ ((size_t)C_*C_)
#define KS_ 8            // split-K factor for stage-1 GEMMs

typedef __bf16 bf16x8 __attribute__((ext_vector_type(8)));
typedef float f32x4 __attribute__((ext_vector_type(4)));

__device__ __forceinline__ float wave64_sum(float v){
#pragma unroll
  for (int d = 1; d < 64; d <<= 1) v += __shfl_xor(v, d, 64);
  return v;
}

// butterfly adds via DPP (VALU pipe, no DS/lgkm involvement)
__device__ __forceinline__ float dpp_add_xor1(float x){
  int j = __builtin_amdgcn_mov_dpp(__float_as_int(x), 0xB1, 0xF, 0xF, true); // quad_perm [1,0,3,2]
  return x + __int_as_float(j);
}
__device__ __forceinline__ float dpp_add_xor2(float x){
  int j = __builtin_amdgcn_mov_dpp(__float_as_int(x), 0x4E, 0xF, 0xF, true); // quad_perm [2,3,0,1]
  return x + __int_as_float(j);
}
__device__ __forceinline__ float dpp_add_hmir(float x){
  int j = __builtin_amdgcn_mov_dpp(__float_as_int(x), 0x141, 0xF, 0xF, true); // row_half_mirror
  return x + __int_as_float(j);
}
__device__ __forceinline__ float dpp_add_mir(float x){
  int j = __builtin_amdgcn_mov_dpp(__float_as_int(x), 0x140, 0xF, 0xF, true); // row_mirror
  return x + __int_as_float(j);
}

// 16-lane row allreduce: xor1, xor2, half_mirror, mirror — all VALU-pipe DPP
__device__ __forceinline__ float red16(float x){
  x = dpp_add_xor1(x);
  x = dpp_add_xor2(x);
  x = dpp_add_hmir(x);
  x = dpp_add_mir(x);
  return x;
}

// bhtn index helper: (b,t) row r in [BT), channel c in [C) -> [B,H,T,64]
__device__ __forceinline__ size_t bhtn_idx(int r, int c){
  return (((size_t)(r >> 10)*H_ + (c >> 6))*T_ + (r & 1023))*64 + (c & 63);
}

// async global->LDS, 16B per lane; dest = wave-uniform base + lane*16
__device__ __forceinline__ void gload_lds16b(const __hip_bfloat16* g, __bf16* l){
  __builtin_amdgcn_global_load_lds((const __attribute__((address_space(1))) void*)g,
                                   (__attribute__((address_space(3))) void*)l, 16, 0, 0);
}

// ---------------- fp32 -> bf16 convert ----------------
__global__ __launch_bounds__(256) void f2bf_kernel(const float* __restrict__ in,
                                                   __hip_bfloat16* __restrict__ out, size_t n){
  size_t i = (size_t)blockIdx.x*256 + threadIdx.x;
  if (i < n) out[i] = __float2bfloat16(in[i]);
}

// ---------------- batched fp32 -> bf16 for 3 weight matrices ----------------
__global__ __launch_bounds__(256) void f2bf3_kernel(const float* __restrict__ i0, const float* __restrict__ i1,
                                                    const float* __restrict__ i2,
                                                    __hip_bfloat16* __restrict__ o0, __hip_bfloat16* __restrict__ o1,
                                                    __hip_bfloat16* __restrict__ o2){
  const int z = blockIdx.y;
  const float* in = (z == 0) ? i0 : (z == 1) ? i1 : i2;
  __hip_bfloat16* out = (z == 0) ? o0 : (z == 1) ? o1 : o2;
  size_t i = (size_t)blockIdx.x*256 + threadIdx.x;
  if (i < CC_) out[i] = __float2bfloat16(in[i]);
}

// ---------------- token shift: xx fp32, xmx bf16; fused x[:,-1] copy ----------------
__global__ __launch_bounds__(256) void shift_kernel(const float* __restrict__ x,
                                                    const float* __restrict__ shift,
                                                    const float* __restrict__ maa_x,
                                                    float* __restrict__ xx, __hip_bfloat16* __restrict__ xmx_h,
                                                    float* __restrict__ out1){
  size_t idx = (size_t)blockIdx.x*256 + threadIdx.x;  // over BTC
  int c = (int)(idx % C_);
  size_t bt = idx / C_;
  int t = (int)(bt % T_);
  int b = (int)(bt / T_);
  float xv = x[idx];
  float prev = (t == 0) ? shift[(size_t)b*C_ + c] : x[idx - C_];
  float d = prev - xv;
  xx[idx] = d;
  xmx_h[idx] = __float2bfloat16(xv + d * maa_x[c]);
  if (t == T_-1) out1[(size_t)b*C_ + c] = xv;
}

// ---------------- batched transpose+convert for the 7 LoRA-W1 weights ----------------
// W[K=2048,Nsrc] fp32 -> rows [row_off..row_off+Nsrc) of panel [128,2048] bf16 in WtB.
// blockIdx.y encodes (cfg, n0-tile): y-ranges {0..3}:maa_w1 {4,5}:dw1 {6}:aw1 {7}:maw1
// {8..11}:gw1 {12}:kkw1 {13}:mkw1.
__global__ __launch_bounds__(256) void tp_pack7(
    const float* __restrict__ w0, const float* __restrict__ w1, const float* __restrict__ w2,
    const float* __restrict__ w3, const float* __restrict__ w4, const float* __restrict__ w5,
    const float* __restrict__ w6, __hip_bfloat16* __restrict__ WtB)
{
  __shared__ float tile[32][33];
  int y = blockIdx.y;
  const float* in; int Nsrc, row_off, panel, yb;
  if      (y < 4)  { in = w0; Nsrc = 128; row_off = 0;  panel = 0; yb = y; }
  else if (y < 6)  { in = w1; Nsrc = 64;  row_off = 0;  panel = 1; yb = y - 4; }
  else if (y < 7)  { in = w2; Nsrc = 16;  row_off = 64; panel = 1; yb = 0; }
  else if (y < 8)  { in = w3; Nsrc = 16;  row_off = 80; panel = 1; yb = 0; }
  else if (y < 12) { in = w4; Nsrc = 128; row_off = 0;  panel = 2; yb = y - 8; }
  else if (y < 13) { in = w5; Nsrc = 16;  row_off = 0;  panel = 3; yb = 0; }
  else             { in = w6; Nsrc = 16;  row_off = 16; panel = 3; yb = 0; }
  __hip_bfloat16* out = WtB + (size_t)panel*128*2048;
  const int t = threadIdx.x;
  const int k0 = blockIdx.x*32, n0 = yb*32;
  const int tn = t & 31, tk = t >> 5;  // tk 0..7
#pragma unroll
  for (int q = 0; q < 4; q++){
    int ki = tk + 8*q;
    float v = (n0 + tn < Nsrc) ? in[(size_t)(k0+ki)*Nsrc + n0 + tn] : 0.f;
    tile[tn][ki] = v;
  }
  __syncthreads();
#pragma unroll
  for (int q = 0; q < 4; q++){
    int no = tk + 8*q;
    if (n0 + no < Nsrc)
      out[(size_t)(row_off + n0 + no)*2048 + k0 + tn] = __float2bfloat16(tile[no][tn]);
  }
}

// ---------------- split-K skinny MFMA GEMM: parts[z] = A[128rows x KC] * B[128, KC]^T ----------------
// 2-phase double-buffered gload_lds pipeline
__global__ __launch_bounds__(256) void gemm_sk(const __hip_bfloat16* __restrict__ Ah,
                                               const __hip_bfloat16* __restrict__ Bh,
                                               float* __restrict__ parts, int K, int KC){
  __shared__ __bf16 As[2][128*32];
  __shared__ __bf16 Bs[2][128*32];
  const int tid = threadIdx.x;
  const int bm = blockIdx.x*128;
  const int z = blockIdx.y;
  const int wid = tid >> 6, lane = tid & 63;
  const int wr = (wid >> 1)*64, wc = (wid & 1)*64;
  const int fr = lane & 15, kg = lane >> 4;
  const int srow = tid >> 2, sk = (tid & 3)*8;
  f32x4 acc[4][4] = {};
  const int kend = z*KC + KC;
#define SK_STAGE(kt_, b_) do{ \
    gload_lds16b(Ah + (size_t)(bm+srow)*K + (kt_) + sk,    As[b_] + wid*512); \
    gload_lds16b(Ah + (size_t)(bm+srow+64)*K + (kt_) + sk, As[b_] + wid*512 + 64*32); \
    gload_lds16b(Bh + (size_t)(srow)*K + (kt_) + sk,       Bs[b_] + wid*512); \
    gload_lds16b(Bh + (size_t)(srow+64)*K + (kt_) + sk,    Bs[b_] + wid*512 + 64*32); \
  }while(0)
  SK_STAGE(z*KC, 0);
  __builtin_amdgcn_s_waitcnt(0x3F70);   // vmcnt(0)
  __builtin_amdgcn_s_barrier();
  __builtin_amdgcn_sched_barrier(0);
  int buf = 0;
  for (int kt = z*KC; kt < kend; kt += 32){
    if (kt + 32 < kend) SK_STAGE(kt+32, buf^1);
    bf16x8 af[4], bfr[4];
#pragma unroll
    for (int i = 0; i < 4; i++){
      af[i]  = *(const bf16x8*)(As[buf] + (wr + i*16 + fr)*32 + kg*8);
      bfr[i] = *(const bf16x8*)(Bs[buf] + (wc + i*16 + fr)*32 + kg*8);
    }
#pragma unroll
    for (int mi = 0; mi < 4; mi++)
#pragma unroll
      for (int ni = 0; ni < 4; ni++)
        acc[mi][ni] = __builtin_amdgcn_mfma_f32_16x16x32_bf16(af[mi], bfr[ni], acc[mi][ni], 0, 0, 0);
    __builtin_amdgcn_sched_barrier(0);
    __builtin_amdgcn_s_waitcnt(0x3F70); // vmcnt(0): next-tile stage landed
    __builtin_amdgcn_s_barrier();
    __builtin_amdgcn_sched_barrier(0);
    buf ^= 1;
  }
#undef SK_STAGE
  float* Cc = parts + (size_t)z*BT_*128;
  const int orow0 = bm + wr + kg*4;
  const int ocol0 = wc + fr;
#pragma unroll
  for (int mi = 0; mi < 4; mi++)
#pragma unroll
    for (int ni = 0; ni < 4; ni++)
#pragma unroll
      for (int j = 0; j < 4; j++)
        Cc[(size_t)(orow0 + mi*16 + j)*128 + ocol0 + ni*16] = acc[mi][ni][j];
}

// ---------------- batched skinny GEMM: 3 independent (A,B,parts) triples via grid.z ----------------
__global__ __launch_bounds__(256) void gemm_sk3(
    const __hip_bfloat16* __restrict__ A0, const __hip_bfloat16* __restrict__ A1,
    const __hip_bfloat16* __restrict__ A2,
    const __hip_bfloat16* __restrict__ B0, const __hip_bfloat16* __restrict__ B1,
    const __hip_bfloat16* __restrict__ B2,
    float* __restrict__ P0, float* __restrict__ P1, float* __restrict__ P2, int K, int KC)
{
  __shared__ __bf16 As[2][128*32];
  __shared__ __bf16 Bs[2][128*32];
  const int zi = blockIdx.z;
  const __hip_bfloat16* Ah = (zi == 0) ? A0 : (zi == 1) ? A1 : A2;
  const __hip_bfloat16* Bh = (zi == 0) ? B0 : (zi == 1) ? B1 : B2;
  float* parts = (zi == 0) ? P0 : (zi == 1) ? P1 : P2;
  const int tid = threadIdx.x;
  const int bm = blockIdx.x*128;
  const int z = blockIdx.y;
  const int wid = tid >> 6, lane = tid & 63;
  const int wr = (wid >> 1)*64, wc = (wid & 1)*64;
  const int fr = lane & 15, kg = lane >> 4;
  const int srow = tid >> 2, sk = (tid & 3)*8;
  f32x4 acc[4][4] = {};
  const int kend = z*KC + KC;
#define SK3_STAGE(kt_, b_) do{ \
    gload_lds16b(Ah + (size_t)(bm+srow)*K + (kt_) + sk,    As[b_] + wid*512); \
    gload_lds16b(Ah + (size_t)(bm+srow+64)*K + (kt_) + sk, As[b_] + wid*512 + 64*32); \
    gload_lds16b(Bh + (size_t)(srow)*K + (kt_) + sk,       Bs[b_] + wid*512); \
    gload_lds16b(Bh + (size_t)(srow+64)*K + (kt_) + sk,    Bs[b_] + wid*512 + 64*32); \
  }while(0)
  SK3_STAGE(z*KC, 0);
  __builtin_amdgcn_s_waitcnt(0x3F70);
  __builtin_amdgcn_s_barrier();
  __builtin_amdgcn_sched_barrier(0);
  int buf = 0;
  for (int kt = z*KC; kt < kend; kt += 32){
    if (kt + 32 < kend) SK3_STAGE(kt+32, buf^1);
    bf16x8 af[4], bfr[4];
#pragma unroll
    for (int i = 0; i < 4; i++){
      af[i]  = *(const bf16x8*)(As[buf] + (wr + i*16 + fr)*32 + kg*8);
      bfr[i] = *(const bf16x8*)(Bs[buf] + (wc + i*16 + fr)*32 + kg*8);
    }
#pragma unroll
    for (int mi = 0; mi < 4; mi++)
#pragma unroll
      for (int ni = 0; ni < 4; ni++)
        acc[mi][ni] = __builtin_amdgcn_mfma_f32_16x16x32_bf16(af[mi], bfr[ni], acc[mi][ni], 0, 0, 0);
    __builtin_amdgcn_sched_barrier(0);
    __builtin_amdgcn_s_waitcnt(0x3F70);
    __builtin_amdgcn_s_barrier();
    __builtin_amdgcn_sched_barrier(0);
    buf ^= 1;
  }
#undef SK3_STAGE
  float* Cc = parts + (size_t)z*BT_*128;
  const int orow0 = bm + wr + kg*4;
  const int ocol0 = wc + fr;
#pragma unroll
  for (int mi = 0; mi < 4; mi++)
#pragma unroll
    for (int ni = 0; ni < 4; ni++)
#pragma unroll
      for (int j = 0; j < 4; j++)
        Cc[(size_t)(orow0 + mi*16 + j)*128 + ocol0 + ni*16] = acc[mi][ni][j];
}

// ---------------- batched reduce for 3 parts sets; z-specific tanh ranges ----------------
__global__ __launch_bounds__(256) void reduce_sk3(const float* __restrict__ P0, const float* __restrict__ P1,
                                                  const float* __restrict__ P2,
                                                  float* __restrict__ O0, float* __restrict__ O1,
                                                  float* __restrict__ O2){
  const int zi = blockIdx.y;
  const float* parts = (zi == 0) ? P0 : (zi == 1) ? P1 : P2;
  float* out = (zi == 0) ? O0 : (zi == 1) ? O1 : O2;
  const int hi = (zi == 0) ? 64 : (zi == 1) ? 128 : 16;   // wa1: 0..64, g1: all, k1: 0..16
  size_t idx = (size_t)blockIdx.x*256 + threadIdx.x;  // BT*128
  float s = 0.f;
#pragma unroll
  for (int z = 0; z < KS_; z++) s += parts[(size_t)z*BT_*128 + idx];
  int c = (int)(idx & 127);
  if (c < hi) s = tanhf(s);
  out[idx] = s;
}

// ---------------- reduce split-K parts + fused tanh on column range ----------------
__global__ __launch_bounds__(256) void reduce_sk(const float* __restrict__ parts, float* __restrict__ out,
                                                 int tanh_lo, int tanh_hi){
  size_t idx = (size_t)blockIdx.x*256 + threadIdx.x;  // BT*128
  float s = 0.f;
#pragma unroll
  for (int z = 0; z < KS_; z++) s += parts[(size_t)z*BT_*128 + idx];
  int c = (int)(idx & 127);
  if (c >= tanh_lo && c < tanh_hi) s = tanhf(s);
  out[idx] = s;
}

// ---------------- g = tanh'd g1[BT,128] @ gw2[128,C] -> bf16 ----------------
__global__ __launch_bounds__(256) void mm_sk_g(const float* __restrict__ A, const float* __restrict__ W,
                                               __hip_bfloat16* __restrict__ out, int K){
  const int j = blockIdx.y*256 + threadIdx.x;
  const int i0 = blockIdx.x*8;
  float acc[8] = {0,0,0,0,0,0,0,0};
  for (int k = 0; k < K; k++){
    float wv = W[(size_t)k*C_ + j];
#pragma unroll
    for (int r = 0; r < 8; r++) acc[r] += A[(size_t)(i0+r)*K + k] * wv;
  }
#pragma unroll
  for (int r = 0; r < 8; r++) out[(size_t)(i0+r)*C_ + j] = __float2bfloat16(acc[r]);
}

// ---------------- maa einsum + mix -> bf16 xrg/xwa/xk/xv ----------------
__global__ __launch_bounds__(256) void mix_kernel(
    const float* __restrict__ m1, const float* __restrict__ w2,
    const float* __restrict__ x, const float* __restrict__ xx,
    const float* __restrict__ maa_rg, const float* __restrict__ maa_wa,
    const float* __restrict__ maa_k, const float* __restrict__ maa_v,
    __hip_bfloat16* __restrict__ xrg_h, __hip_bfloat16* __restrict__ xwa_h,
    __hip_bfloat16* __restrict__ xk_h, __hip_bfloat16* __restrict__ xv_h)
{
  const int j = blockIdx.y*256 + threadIdx.x;
  const int i0 = blockIdx.x*8;
  float acc[4][8] = {};
#pragma unroll
  for (int f = 0; f < 4; f++){
    for (int d = 0; d < 32; d++){
      float wv = w2[((size_t)f*32 + d)*C_ + j];
#pragma unroll
      for (int r = 0; r < 8; r++)
        acc[f][r] += m1[(size_t)(i0+r)*128 + f*32 + d] * wv;
    }
  }
  float mrg_ = maa_rg[j], mwa_ = maa_wa[j], mk_ = maa_k[j], mv_ = maa_v[j];
#pragma unroll
  for (int r = 0; r < 8; r++){
    size_t idx = (size_t)(i0+r)*C_ + j;
    float xval = x[idx], xxv = xx[idx];
    xrg_h[idx] = __float2bfloat16(xval + xxv*(mrg_ + acc[0][r]));
    xwa_h[idx] = __float2bfloat16(xval + xxv*(mwa_ + acc[1][r]));
    xk_h[idx]  = __float2bfloat16(xval + xxv*(mk_  + acc[2][r]));
    xv_h[idx]  = __float2bfloat16(xval + xxv*(mv_  + acc[3][r]));
  }
}

// ---------------- bf16 MFMA GEMM: C[M,N] = A[M,K] * B[N,K]^T (fp32 out, btc layout) ----------------
// 2-phase double-buffered gload_lds pipeline
__global__ __launch_bounds__(256) void gemm_bt(const __hip_bfloat16* __restrict__ Ah,
                                               const __hip_bfloat16* __restrict__ Bh,
                                               float* __restrict__ Cc, int M, int Nn, int K){
  __shared__ __bf16 As[2][128*32];
  __shared__ __bf16 Bs[2][128*32];
  const int tid = threadIdx.x;
  const int bm = blockIdx.x*128, bn = blockIdx.y*128;
  const int wid = tid >> 6, lane = tid & 63;
  const int wr = (wid >> 1)*64, wc = (wid & 1)*64;
  const int fr = lane & 15, kg = lane >> 4;
  const int srow = tid >> 2, sk = (tid & 3)*8;
  f32x4 acc[4][4] = {};
#define BT_STAGE(kt_, b_) do{ \
    gload_lds16b(Ah + (size_t)(bm+srow)*K + (kt_) + sk,    As[b_] + wid*512); \
    gload_lds16b(Ah + (size_t)(bm+srow+64)*K + (kt_) + sk, As[b_] + wid*512 + 64*32); \
    gload_lds16b(Bh + (size_t)(bn+srow)*K + (kt_) + sk,    Bs[b_] + wid*512); \
    gload_lds16b(Bh + (size_t)(bn+srow+64)*K + (kt_) + sk, Bs[b_] + wid*512 + 64*32); \
  }while(0)
  BT_STAGE(0, 0);
  __builtin_amdgcn_s_waitcnt(0x3F70);
  __builtin_amdgcn_s_barrier();
  __builtin_amdgcn_sched_barrier(0);
  int buf = 0;
  for (int kt = 0; kt < K; kt += 32){
    if (kt + 32 < K) BT_STAGE(kt+32, buf^1);
    bf16x8 af[4], bfr[4];
#pragma unroll
    for (int i = 0; i < 4; i++){
      af[i]  = *(const bf16x8*)(As[buf] + (wr + i*16 + fr)*32 + kg*8);
      bfr[i] = *(const bf16x8*)(Bs[buf] + (wc + i*16 + fr)*32 + kg*8);
    }
#pragma unroll
    for (int mi = 0; mi < 4; mi++)
#pragma unroll
      for (int ni = 0; ni < 4; ni++)
        acc[mi][ni] = __builtin_amdgcn_mfma_f32_16x16x32_bf16(af[mi], bfr[ni], acc[mi][ni], 0, 0, 0);
    __builtin_amdgcn_sched_barrier(0);
    __builtin_amdgcn_s_waitcnt(0x3F70);
    __builtin_amdgcn_s_barrier();
    __builtin_amdgcn_sched_barrier(0);
    buf ^= 1;
  }
#undef BT_STAGE
  const int orow0 = bm + wr + kg*4;
  const int ocol0 = bn + wc + fr;
#pragma unroll
  for (int mi = 0; mi < 4; mi++)
#pragma unroll
    for (int ni = 0; ni < 4; ni++)
#pragma unroll
      for (int j = 0; j < 4; j++)
        Cc[(size_t)(orow0 + mi*16 + j)*Nn + ocol0 + ni*16] = acc[mi][ni][j];
}

// ---------------- batched r/k/v GEMM, C in [B,H,T,64] (bhtn) layout, grid.z selects triple ----------------
__global__ __launch_bounds__(256) void gemm_bt_T3(
    const __hip_bfloat16* __restrict__ A0, const __hip_bfloat16* __restrict__ A1,
    const __hip_bfloat16* __restrict__ A2,
    const __hip_bfloat16* __restrict__ B0, const __hip_bfloat16* __restrict__ B1,
    const __hip_bfloat16* __restrict__ B2,
    float* __restrict__ C0, float* __restrict__ C1, float* __restrict__ C2, int K)
{
  __shared__ __bf16 As[2][128*32];
  __shared__ __bf16 Bs[2][128*32];
  const int zi = blockIdx.z;
  const __hip_bfloat16* Ah = (zi == 0) ? A0 : (zi == 1) ? A1 : A2;
  const __hip_bfloat16* Bh = (zi == 0) ? B0 : (zi == 1) ? B1 : B2;
  float* Cc = (zi == 0) ? C0 : (zi == 1) ? C1 : C2;
  const int tid = threadIdx.x;
  const int bm = blockIdx.x*128, bn = blockIdx.y*128;
  const int wid = tid >> 6, lane = tid & 63;
  const int wr = (wid >> 1)*64, wc = (wid & 1)*64;
  const int fr = lane & 15, kg = lane >> 4;
  const int srow = tid >> 2, sk = (tid & 3)*8;
  f32x4 acc[4][4] = {};
#define T3_STAGE(kt_, b_) do{ \
    gload_lds16b(Ah + (size_t)(bm+srow)*K + (kt_) + sk,    As[b_] + wid*512); \
    gload_lds16b(Ah + (size_t)(bm+srow+64)*K + (kt_) + sk, As[b_] + wid*512 + 64*32); \
    gload_lds16b(Bh + (size_t)(bn+srow)*K + (kt_) + sk,    Bs[b_] + wid*512); \
    gload_lds16b(Bh + (size_t)(bn+srow+64)*K + (kt_) + sk, Bs[b_] + wid*512 + 64*32); \
  }while(0)
  T3_STAGE(0, 0);
  __builtin_amdgcn_s_waitcnt(0x3F70);
  __builtin_amdgcn_s_barrier();
  __builtin_amdgcn_sched_barrier(0);
  int buf = 0;
  for (int kt = 0; kt < K; kt += 32){
    if (kt + 32 < K) T3_STAGE(kt+32, buf^1);
    bf16x8 af[4], bfr[4];
#pragma unroll
    for (int i = 0; i < 4; i++){
      af[i]  = *(const bf16x8*)(As[buf] + (wr + i*16 + fr)*32 + kg*8);
      bfr[i] = *(const bf16x8*)(Bs[buf] + (wc + i*16 + fr)*32 + kg*8);
    }
#pragma unroll
    for (int mi = 0; mi < 4; mi++)
#pragma unroll
      for (int ni = 0; ni < 4; ni++)
        acc[mi][ni] = __builtin_amdgcn_mfma_f32_16x16x32_bf16(af[mi], bfr[ni], acc[mi][ni], 0, 0, 0);
    __builtin_amdgcn_sched_barrier(0);
    __builtin_amdgcn_s_waitcnt(0x3F70);
    __builtin_amdgcn_s_barrier();
    __builtin_amdgcn_sched_barrier(0);
    buf ^= 1;
  }
#undef T3_STAGE
  const int r0 = bm + wr + kg*4;
  const int c0 = bn + wc + fr;
#pragma unroll
  for (int mi = 0; mi < 4; mi++)
#pragma unroll
    for (int ni = 0; ni < 4; ni++)
#pragma unroll
      for (int j = 0; j < 4; j++)
        Cc[bhtn_idx(r0 + mi*16 + j, c0 + ni*16)] = acc[mi][ni][j];
}

// ---------------- fused LoRA stage-2 + decay/gates + kk-normalize + b=kk*a (writes bhtn) ----------------
// wa1[BT,128]: cols 0..63 = tanh(d1), 64..79 = a1, 80..95 = ma1
// k1c[BT,128]: cols 0..15 = tanh(kk1), 16..31 = mk1
// Wave = 64 consecutive channels = one head (j base 64-aligned) -> per-head L2 norm in-register.
__global__ __launch_bounds__(256) void lora2_kernel(
    const float* __restrict__ wa1, const float* __restrict__ k1c,
    const float* __restrict__ dw2, const float* __restrict__ aw2, const float* __restrict__ maw2,
    const float* __restrict__ mkw2, const float* __restrict__ kkw2,
    const float* __restrict__ td, const float* __restrict__ aaaaa,
    const float* __restrict__ misc_a, const float* __restrict__ misc_k,
    float* __restrict__ k0, float* __restrict__ b_out,
    float* __restrict__ ew_out, float* __restrict__ kk0_out)
{
  const int j = blockIdx.y*256 + threadIdx.x;
  const int i0 = blockIdx.x*8;
  float accW[8] = {}, accA[8] = {}, accMA[8] = {}, accMK[8] = {}, accKK[8] = {};
  for (int k = 0; k < 64; k++){
    float wv = dw2[(size_t)k*C_ + j];
#pragma unroll
    for (int r = 0; r < 8; r++) accW[r] += wa1[(size_t)(i0+r)*128 + k] * wv;
  }
  for (int k = 0; k < 16; k++){
    float w_a  = aw2[(size_t)k*C_ + j];
    float w_ma = maw2[(size_t)k*C_ + j];
    float w_mk = mkw2[(size_t)k*C_ + j];
    float w_kk = kkw2[(size_t)k*C_ + j];
#pragma unroll
    for (int r = 0; r < 8; r++){
      accA[r]  += wa1[(size_t)(i0+r)*128 + 64 + k] * w_a;
      accMA[r] += wa1[(size_t)(i0+r)*128 + 80 + k] * w_ma;
      accKK[r] += k1c[(size_t)(i0+r)*128 + k] * w_kk;
      accMK[r] += k1c[(size_t)(i0+r)*128 + 16 + k] * w_mk;
    }
  }
  float tdv = td[j], aav = aaaaa[j], mav = misc_a[j], mkv = misc_k[j];
#pragma unroll
  for (int r = 0; r < 8; r++){
    size_t idx = bhtn_idx(i0+r, j);
    float u  = tdv + accW[r];
    float w  = -log1pf(expf(-u)) - 0.5f;               // -softplus(-u) - 0.5
    float a  = 1.f/(1.f + expf(-(aav + accA[r])));
    float ma = 1.f/(1.f + expf(-(mav + accMA[r])));
    float mk = 1.f/(1.f + expf(-(mkv + accMK[r])));
    float kv = k0[idx];
    float kk = kv + accKK[r];
    // fused per-head normalize: this wave's 64 lanes ARE this head's 64 channels for row i0+r
    float ss  = wave64_sum(kk*kk);
    float kkn = kk / fmaxf(sqrtf(ss), 1e-12f);
    kk0_out[idx] = kkn;
    b_out[idx]   = kkn * a;
    float kn = kv * (ma + a*(1.f - ma)) * expf(fminf(w*mk, 0.f));
    k0[idx] = kn;
    ew_out[idx] = expf(w);
  }
}

// ---------------- RWKV-7 recurrence: 1024 blocks x 64 threads, direct global->reg prefetch ----------------
// Lane map: cf = lane>>4 (v-column 0..3), kq = lane&15 (k-group, 4 k's). Streams load directly
// global->regs (coalesced 16B/lane-group slices; 16 blocks/bh share XCD-local L2), 3-step
// register prefetch ring. Output STORES are de-entangled from the load vmcnt chain: red16 is an
// allreduce, so lane kq==s banks step tb+s's op; ONE 64-lane store per 16-step window
// (was 1 strided store per step -> 16x fewer vmcnt store entries blocking load waits).
__global__ __launch_bounds__(64, 1) void rec_kernel(
    const float* __restrict__ rr, const float* __restrict__ kx,
    const float* __restrict__ vx, const float* __restrict__ ew,
    const float* __restrict__ kkv, const float* __restrict__ bsv,
    const float* __restrict__ s0, float* __restrict__ o, float* __restrict__ sT)
{
  const int g = blockIdx.x;            // 1024 = vg*64 + bh  (g%8==bh%8 -> XCD-local sharing)
  const int bh = g & 63;
  const int vg = g >> 6;               // 0..15
  const int b = bh >> 5, h = bh & 31;
  const int lane = threadIdx.x;
  const int cf = lane >> 4;            // v-column within block (DPP row id)
  const int kq = lane & 15;            // k-group (4 consecutive k)
  const int k0 = kq*4;
  const int v = vg*4 + cf;

  float S0, S1, S2, S3;
  {
    const float* p = s0 + ((size_t)bh*64 + k0)*64 + v;
    S0 = p[0]; S1 = p[64]; S2 = p[128]; S3 = p[192];
  }

  const size_t sb = (size_t)bh*T_*64;  // stream base (bhtn)
  const float* gA = kkv + sb + k0;     // a
  const float* gE = ew  + sb + k0;     // e
  const float* gK = kx  + sb + k0;     // k
  const float* gB = bsv + sb + k0;     // b
  const float* gR = rr  + sb + k0;     // r
  const float* gV = vx  + sb + v;      // v (per-lane column)
  // batched-store base: lane (cf,kq) writes o[b, tb+kq, h*64 + vg*4 + cf]
  float* obw = o + (size_t)b*T_*C_ + h*64 + v + (size_t)kq*C_;   // + tb*C_

  float4 Aq[4], Eq[4], Kq[4], Bq[4], Rq[4];
  float  Vq[4];

#define LOADT(t_, sl_) do{ \
    Aq[sl_] = *(const float4*)(gA + (size_t)(t_)*64); \
    Eq[sl_] = *(const float4*)(gE + (size_t)(t_)*64); \
    Kq[sl_] = *(const float4*)(gK + (size_t)(t_)*64); \
    Bq[sl_] = *(const float4*)(gB + (size_t)(t_)*64); \
    Rq[sl_] = *(const float4*)(gR + (size_t)(t_)*64); \
    Vq[sl_] = gV[(size_t)(t_)*64]; \
  }while(0)

  LOADT(0, 0); LOADT(1, 1); LOADT(2, 2);

  for (int tb = 0; tb < T_; tb += 16){
    float opv = 0.f;
#pragma unroll
    for (int s = 0; s < 16; s++){
      const int t = tb + s;
      const int tn = (t + 3 < T_) ? (t + 3) : (T_ - 1);   // tail re-load is harmless
      LOADT(tn, (s + 3) & 3);
      const float4 A  = Aq[s & 3];
      const float4 E  = Eq[s & 3];
      const float4 Kk = Kq[s & 3];
      const float4 Bv = Bq[s & 3];
      const float4 R  = Rq[s & 3];
      const float  vt = Vq[s & 3];
      float p = (A.x*S0 + A.y*S1) + (A.z*S2 + A.w*S3);
      p = red16(p);                      // sa = -p (folded into the update)
      S0 = S0*E.x + Kk.x*vt - Bv.x*p;
      S1 = S1*E.y + Kk.y*vt - Bv.y*p;
      S2 = S2*E.z + Kk.z*vt - Bv.z*p;
      S3 = S3*E.w + Kk.w*vt - Bv.w*p;
      float op = (R.x*S0 + R.y*S1) + (R.z*S2 + R.w*S3);
      op = red16(op);                    // allreduce: every lane holds the sum
      if (kq == s) opv = op;             // bank step tb+s in lane kq==s (cndmask)
    }
    obw[(size_t)tb*C_] = opv;            // one 64-lane store per 16-step window
  }
#undef LOADT
  float* pT = sT + ((size_t)bh*64 + k0)*64 + v;
  pT[0] = S0; pT[64] = S1; pT[128] = S2; pT[192] = S3;
}

// ---------------- GroupNorm + faaaa term + *g -> z (bf16) ----------------
// o,g,z in btc layout; r,k,v in bhtn layout.
__global__ __launch_bounds__(256) void post_kernel(
    const float* __restrict__ o, const float* __restrict__ r, const float* __restrict__ k,
    const float* __restrict__ v, const __hip_bfloat16* __restrict__ g,
    const float* __restrict__ lnw, const float* __restrict__ lnb,
    const float* __restrict__ faaaa, __hip_bfloat16* __restrict__ z_h)
{
  const size_t grp = (size_t)blockIdx.x*4 + (threadIdx.x >> 6);  // bt*H + h
  const int lane = threadIdx.x & 63;
  const int h = (int)(grp & (H_-1));
  const int bt = (int)(grp >> 5);
  const size_t idx  = grp*64 + lane;                              // btc
  const size_t idx2 = (((size_t)(bt >> 10)*H_ + h)*T_ + (bt & 1023))*64 + lane;  // bhtn
  const int ci = h*64 + lane;
  float y = o[idx];
  float mu = wave64_sum(y) * (1.f/64.f);
  float d = y - mu;
  float var = wave64_sum(d*d) * (1.f/64.f);
  float yn = d * rsqrtf(var + 64e-5f) * lnw[ci] + lnb[ci];
  float s = wave64_sum(r[idx2]*k[idx2]*faaaa[ci]);
  float xo = yn + s*v[idx2];
  z_h[idx] = __float2bfloat16(xo * __bfloat162float(g[idx]));
}

extern "C" void kernel_launch(void* const* d_in, const int* in_sizes, int n_in,
                              void* d_out, int out_size, void* d_ws, size_t ws_size,
                              hipStream_t stream){
  (void)in_sizes; (void)n_in; (void)out_size;
  const float* x      = (const float*)d_in[0];
  const float* shift  = (const float*)d_in[1];
  const float* wkv0   = (const float*)d_in[2];
  const float* maa_x  = (const float*)d_in[3];
  const float* maa_rg = (const float*)d_in[4];
  const float* maa_wa = (const float*)d_in[5];
  const float* maa_k  = (const float*)d_in[6];
  const float* maa_v  = (const float*)d_in[7];
  const float* maa_w1 = (const float*)d_in[8];
  const float* maa_w2 = (const float*)d_in[9];
  const float* tdecay = (const float*)d_in[10];
  const float* dw1    = (const float*)d_in[11];
  const float* dw2    = (const float*)d_in[12];
  const float* faaaa  = (const float*)d_in[13];
  const float* aaaaa  = (const float*)d_in[14];
  const float* aw1    = (const float*)d_in[15];
  const float* aw2    = (const float*)d_in[16];
  const float* kkw1   = (const float*)d_in[17];
  const float* kkw2   = (const float*)d_in[18];
  const float* gw1    = (const float*)d_in[19];
  const float* gw2    = (const float*)d_in[20];
  const float* maw1   = (const float*)d_in[21];
  const float* maw2   = (const float*)d_in[22];
  const float* misc_a = (const float*)d_in[23];
  const float* mkw1   = (const float*)d_in[24];
  const float* mkw2   = (const float*)d_in[25];
  const float* misc_k = (const float*)d_in[26];
  const float* Wr     = (const float*)d_in[27];
  const float* Wk     = (const float*)d_in[28];
  const float* Wv     = (const float*)d_in[29];
  const float* Wo     = (const float*)d_in[30];
  const float* lnw    = (const float*)d_in[31];
  const float* lnb    = (const float*)d_in[32];

  float* out0 = (float*)d_out;                 // [B,T,C]  (also holds o pre-epilogue)
  float* out1 = out0 + BTC_;                   // [B,C]
  float* outS = out1 + (size_t)B_*C_;          // [B,H,N,N]

  const size_t NEEDED = (6*BTC_ + (size_t)3*BT_*128)*4 + 5*CC_*2 + (size_t)4*128*2048*2;
  if (ws_size < NEEDED) return;

  float* ws = (float*)d_ws;
  float* rbuf  = ws;            // bhtn
  float* kbuf  = ws + 1*BTC_;   // bhtn
  float* vbuf  = ws + 2*BTC_;   // bhtn
  float* abuf  = ws + 3*BTC_;   // b_s (bhtn); early alias: xx (btc)
  float* ewbuf = ws + 4*BTC_;   // exp(w) (bhtn); early alias: Wk_h
  float* kkbuf = ws + 5*BTC_;   // kk (bhtn);     early alias: Wv_h
  float* xx    = abuf;
  float* wa1   = ws + 6*BTC_;
  float* g1f   = wa1 + (size_t)BT_*128;
  float* k1c   = g1f + (size_t)BT_*128;
  float* parts = rbuf;
  float* m1f   = vbuf;
  __hip_bfloat16* hb = (__hip_bfloat16*)(k1c + (size_t)BT_*128);
  __hip_bfloat16* xrg_h = hb;
  __hip_bfloat16* xwa_h = hb + 1*CC_;
  __hip_bfloat16* xk_h  = hb + 2*CC_;
  __hip_bfloat16* xv_h  = hb + 3*CC_;
  __hip_bfloat16* Wb    = hb + 4*CC_;
  __hip_bfloat16* WtB   = hb + 5*CC_;
  __hip_bfloat16* Wt_m  = WtB;
  __hip_bfloat16* Wt_wa = WtB + (size_t)128*2048;
  __hip_bfloat16* Wt_g  = WtB + (size_t)2*128*2048;
  __hip_bfloat16* Wt_k  = WtB + (size_t)3*128*2048;
  __hip_bfloat16* xmx_h = xv_h;
  __hip_bfloat16* g_h   = xwa_h;
  __hip_bfloat16* z_h   = xv_h;
  __hip_bfloat16* Wk_h  = (__hip_bfloat16*)ewbuf;
  __hip_bfloat16* Wv_h  = (__hip_bfloat16*)kkbuf;

  dim3 blk(256);
  const int KC = C_/KS_;

  hipMemsetAsync(WtB, 0, (size_t)4*128*2048*2, stream);
  tp_pack7<<<dim3(64, 14), blk, 0, stream>>>(maa_w1, dw1, aw1, maw1, gw1, kkw1, mkw1, WtB);

  shift_kernel<<<(int)(BTC_/256), blk, 0, stream>>>(x, shift, maa_x, xx, xmx_h, out1);

  gemm_sk<<<dim3(BT_/128, KS_), blk, 0, stream>>>(xmx_h, Wt_m, parts, C_, KC);
  reduce_sk<<<BT_*128/256, blk, 0, stream>>>(parts, m1f, 0, 128);

  mix_kernel<<<dim3(BT_/8, C_/256), blk, 0, stream>>>(m1f, maa_w2, x, xx, maa_rg, maa_wa, maa_k, maa_v,
                                                      xrg_h, xwa_h, xk_h, xv_h);

  // 3 independent skinny GEMMs batched: (xwa,Wt_wa)->P0(rbuf), (xrg,Wt_g)->P1(kbuf), (xk,Wt_k)->P2(vbuf)
  gemm_sk3<<<dim3(BT_/128, KS_, 3), blk, 0, stream>>>(xwa_h, xrg_h, xk_h,
                                                      Wt_wa, Wt_g, Wt_k,
                                                      rbuf, kbuf, vbuf, C_, KC);
  reduce_sk3<<<dim3(BT_*128/256, 3), blk, 0, stream>>>(rbuf, kbuf, vbuf, wa1, g1f, k1c);

  mm_sk_g<<<dim3(BT_/8, C_/256), blk, 0, stream>>>(g1f, gw2, g_h, 128);

  f2bf3_kernel<<<dim3((int)(CC_/256), 3), blk, 0, stream>>>(Wr, Wk, Wv, Wb, Wk_h, Wv_h);
  gemm_bt_T3<<<dim3(BT_/128, C_/128, 3), blk, 0, stream>>>(xrg_h, xk_h, xv_h,
                                                           Wb, Wk_h, Wv_h,
                                                           rbuf, kbuf, vbuf, C_);

  lora2_kernel<<<dim3(BT_/8, C_/256), blk, 0, stream>>>(wa1, k1c,
                                                        dw2, aw2, maw2, mkw2, kkw2,
                                                        tdecay, aaaaa, misc_a, misc_k,
                                                        kbuf, abuf, ewbuf, kkbuf);

  rec_kernel<<<1024, dim3(64), 0, stream>>>(rbuf, kbuf, vbuf, ewbuf, kkbuf, abuf, wkv0, out0, outS);

  post_kernel<<<BT_*H_/4, blk, 0, stream>>>(out0, rbuf, kbuf, vbuf, g_h, lnw, lnb, faaaa, z_h);
  f2bf_kernel<<<(int)(CC_/256), blk, 0, stream>>>(Wo, Wb, CC_);
  gemm_bt<<<dim3(BT_/128, C_/128), blk, 0, stream>>>(z_h, Wb, out0, BT_, C_, C_);
}

// Round 10
// 704.322 us; speedup vs baseline: 1.1195x; 1.1195x over previous
//
#include <hip/hip_runtime.h>
#include <hip/hip_bf16.h>
#include <math.h>

// RWKV-7 Tmix forward, MI355X/gfx950.
// B=2 T=1024 C=2048 H=32 N=64. Outputs: xo [B,T,C], x[:,-1] [B,C], S_final [B,H,N,N].
// R16: rec = R14 structure (direct global->reg, per-step kq==0 store; benched 203us)
//      with the prefetch ring deepened 4->8 slots (42 loads in flight; Little's law vs
//      ~900cy HBM latency on the ~50% L2-miss fraction). Unroll-by-8 keeps slot indices
//      compile-time (R15's unroll-16 let the compiler compress the ring -> regression).
//      Host-side wins kept: tp_pack7, lastx fused into shift.

#define B_ 2
#define T_ 1024
#define C_ 2048
#define H_ 32
#define BT_ (B_*T_)
#define BTC_ ((size_t)BT_*C_)
#define CC_ ((size_t)C_*C_)
#define KS_ 8            // split-K factor for stage-1 GEMMs

typedef __bf16 bf16x8 __attribute__((ext_vector_type(8)));
typedef float f32x4 __attribute__((ext_vector_type(4)));

__device__ __forceinline__ float wave64_sum(float v){
#pragma unroll
  for (int d = 1; d < 64; d <<= 1) v += __shfl_xor(v, d, 64);
  return v;
}

// butterfly adds via DPP (VALU pipe, no DS/lgkm involvement)
__device__ __forceinline__ float dpp_add_xor1(float x){
  int j = __builtin_amdgcn_mov_dpp(__float_as_int(x), 0xB1, 0xF, 0xF, true); // quad_perm [1,0,3,2]
  return x + __int_as_float(j);
}
__device__ __forceinline__ float dpp_add_xor2(float x){
  int j = __builtin_amdgcn_mov_dpp(__float_as_int(x), 0x4E, 0xF, 0xF, true); // quad_perm [2,3,0,1]
  return x + __int_as_float(j);
}
__device__ __forceinline__ float dpp_add_hmir(float x){
  int j = __builtin_amdgcn_mov_dpp(__float_as_int(x), 0x141, 0xF, 0xF, true); // row_half_mirror
  return x + __int_as_float(j);
}
__device__ __forceinline__ float dpp_add_mir(float x){
  int j = __builtin_amdgcn_mov_dpp(__float_as_int(x), 0x140, 0xF, 0xF, true); // row_mirror
  return x + __int_as_float(j);
}

// 16-lane row allreduce: xor1, xor2, half_mirror, mirror — all VALU-pipe DPP
__device__ __forceinline__ float red16(float x){
  x = dpp_add_xor1(x);
  x = dpp_add_xor2(x);
  x = dpp_add_hmir(x);
  x = dpp_add_mir(x);
  return x;
}

// bhtn index helper: (b,t) row r in [BT), channel c in [C) -> [B,H,T,64]
__device__ __forceinline__ size_t bhtn_idx(int r, int c){
  return (((size_t)(r >> 10)*H_ + (c >> 6))*T_ + (r & 1023))*64 + (c & 63);
}

// async global->LDS, 16B per lane; dest = wave-uniform base + lane*16
__device__ __forceinline__ void gload_lds16b(const __hip_bfloat16* g, __bf16* l){
  __builtin_amdgcn_global_load_lds((const __attribute__((address_space(1))) void*)g,
                                   (__attribute__((address_space(3))) void*)l, 16, 0, 0);
}

// ---------------- fp32 -> bf16 convert ----------------
__global__ __launch_bounds__(256) void f2bf_kernel(const float* __restrict__ in,
                                                   __hip_bfloat16* __restrict__ out, size_t n){
  size_t i = (size_t)blockIdx.x*256 + threadIdx.x;
  if (i < n) out[i] = __float2bfloat16(in[i]);
}

// ---------------- batched fp32 -> bf16 for 3 weight matrices ----------------
__global__ __launch_bounds__(256) void f2bf3_kernel(const float* __restrict__ i0, const float* __restrict__ i1,
                                                    const float* __restrict__ i2,
                                                    __hip_bfloat16* __restrict__ o0, __hip_bfloat16* __restrict__ o1,
                                                    __hip_bfloat16* __restrict__ o2){
  const int z = blockIdx.y;
  const float* in = (z == 0) ? i0 : (z == 1) ? i1 : i2;
  __hip_bfloat16* out = (z == 0) ? o0 : (z == 1) ? o1 : o2;
  size_t i = (size_t)blockIdx.x*256 + threadIdx.x;
  if (i < CC_) out[i] = __float2bfloat16(in[i]);
}

// ---------------- token shift: xx fp32, xmx bf16; fused x[:,-1] copy ----------------
__global__ __launch_bounds__(256) void shift_kernel(const float* __restrict__ x,
                                                    const float* __restrict__ shift,
                                                    const float* __restrict__ maa_x,
                                                    float* __restrict__ xx, __hip_bfloat16* __restrict__ xmx_h,
                                                    float* __restrict__ out1){
  size_t idx = (size_t)blockIdx.x*256 + threadIdx.x;  // over BTC
  int c = (int)(idx % C_);
  size_t bt = idx / C_;
  int t = (int)(bt % T_);
  int b = (int)(bt / T_);
  float xv = x[idx];
  float prev = (t == 0) ? shift[(size_t)b*C_ + c] : x[idx - C_];
  float d = prev - xv;
  xx[idx] = d;
  xmx_h[idx] = __float2bfloat16(xv + d * maa_x[c]);
  if (t == T_-1) out1[(size_t)b*C_ + c] = xv;
}

// ---------------- batched transpose+convert for the 7 LoRA-W1 weights ----------------
// W[K=2048,Nsrc] fp32 -> rows [row_off..row_off+Nsrc) of panel [128,2048] bf16 in WtB.
// blockIdx.y encodes (cfg, n0-tile): y-ranges {0..3}:maa_w1 {4,5}:dw1 {6}:aw1 {7}:maw1
// {8..11}:gw1 {12}:kkw1 {13}:mkw1.
__global__ __launch_bounds__(256) void tp_pack7(
    const float* __restrict__ w0, const float* __restrict__ w1, const float* __restrict__ w2,
    const float* __restrict__ w3, const float* __restrict__ w4, const float* __restrict__ w5,
    const float* __restrict__ w6, __hip_bfloat16* __restrict__ WtB)
{
  __shared__ float tile[32][33];
  int y = blockIdx.y;
  const float* in; int Nsrc, row_off, panel, yb;
  if      (y < 4)  { in = w0; Nsrc = 128; row_off = 0;  panel = 0; yb = y; }
  else if (y < 6)  { in = w1; Nsrc = 64;  row_off = 0;  panel = 1; yb = y - 4; }
  else if (y < 7)  { in = w2; Nsrc = 16;  row_off = 64; panel = 1; yb = 0; }
  else if (y < 8)  { in = w3; Nsrc = 16;  row_off = 80; panel = 1; yb = 0; }
  else if (y < 12) { in = w4; Nsrc = 128; row_off = 0;  panel = 2; yb = y - 8; }
  else if (y < 13) { in = w5; Nsrc = 16;  row_off = 0;  panel = 3; yb = 0; }
  else             { in = w6; Nsrc = 16;  row_off = 16; panel = 3; yb = 0; }
  __hip_bfloat16* out = WtB + (size_t)panel*128*2048;
  const int t = threadIdx.x;
  const int k0 = blockIdx.x*32, n0 = yb*32;
  const int tn = t & 31, tk = t >> 5;  // tk 0..7
#pragma unroll
  for (int q = 0; q < 4; q++){
    int ki = tk + 8*q;
    float v = (n0 + tn < Nsrc) ? in[(size_t)(k0+ki)*Nsrc + n0 + tn] : 0.f;
    tile[tn][ki] = v;
  }
  __syncthreads();
#pragma unroll
  for (int q = 0; q < 4; q++){
    int no = tk + 8*q;
    if (n0 + no < Nsrc)
      out[(size_t)(row_off + n0 + no)*2048 + k0 + tn] = __float2bfloat16(tile[no][tn]);
  }
}

// ---------------- split-K skinny MFMA GEMM: parts[z] = A[128rows x KC] * B[128, KC]^T ----------------
// 2-phase double-buffered gload_lds pipeline
__global__ __launch_bounds__(256) void gemm_sk(const __hip_bfloat16* __restrict__ Ah,
                                               const __hip_bfloat16* __restrict__ Bh,
                                               float* __restrict__ parts, int K, int KC){
  __shared__ __bf16 As[2][128*32];
  __shared__ __bf16 Bs[2][128*32];
  const int tid = threadIdx.x;
  const int bm = blockIdx.x*128;
  const int z = blockIdx.y;
  const int wid = tid >> 6, lane = tid & 63;
  const int wr = (wid >> 1)*64, wc = (wid & 1)*64;
  const int fr = lane & 15, kg = lane >> 4;
  const int srow = tid >> 2, sk = (tid & 3)*8;
  f32x4 acc[4][4] = {};
  const int kend = z*KC + KC;
#define SK_STAGE(kt_, b_) do{ \
    gload_lds16b(Ah + (size_t)(bm+srow)*K + (kt_) + sk,    As[b_] + wid*512); \
    gload_lds16b(Ah + (size_t)(bm+srow+64)*K + (kt_) + sk, As[b_] + wid*512 + 64*32); \
    gload_lds16b(Bh + (size_t)(srow)*K + (kt_) + sk,       Bs[b_] + wid*512); \
    gload_lds16b(Bh + (size_t)(srow+64)*K + (kt_) + sk,    Bs[b_] + wid*512 + 64*32); \
  }while(0)
  SK_STAGE(z*KC, 0);
  __builtin_amdgcn_s_waitcnt(0x3F70);   // vmcnt(0)
  __builtin_amdgcn_s_barrier();
  __builtin_amdgcn_sched_barrier(0);
  int buf = 0;
  for (int kt = z*KC; kt < kend; kt += 32){
    if (kt + 32 < kend) SK_STAGE(kt+32, buf^1);
    bf16x8 af[4], bfr[4];
#pragma unroll
    for (int i = 0; i < 4; i++){
      af[i]  = *(const bf16x8*)(As[buf] + (wr + i*16 + fr)*32 + kg*8);
      bfr[i] = *(const bf16x8*)(Bs[buf] + (wc + i*16 + fr)*32 + kg*8);
    }
#pragma unroll
    for (int mi = 0; mi < 4; mi++)
#pragma unroll
      for (int ni = 0; ni < 4; ni++)
        acc[mi][ni] = __builtin_amdgcn_mfma_f32_16x16x32_bf16(af[mi], bfr[ni], acc[mi][ni], 0, 0, 0);
    __builtin_amdgcn_sched_barrier(0);
    __builtin_amdgcn_s_waitcnt(0x3F70); // vmcnt(0): next-tile stage landed
    __builtin_amdgcn_s_barrier();
    __builtin_amdgcn_sched_barrier(0);
    buf ^= 1;
  }
#undef SK_STAGE
  float* Cc = parts + (size_t)z*BT_*128;
  const int orow0 = bm + wr + kg*4;
  const int ocol0 = wc + fr;
#pragma unroll
  for (int mi = 0; mi < 4; mi++)
#pragma unroll
    for (int ni = 0; ni < 4; ni++)
#pragma unroll
      for (int j = 0; j < 4; j++)
        Cc[(size_t)(orow0 + mi*16 + j)*128 + ocol0 + ni*16] = acc[mi][ni][j];
}

// ---------------- batched skinny GEMM: 3 independent (A,B,parts) triples via grid.z ----------------
__global__ __launch_bounds__(256) void gemm_sk3(
    const __hip_bfloat16* __restrict__ A0, const __hip_bfloat16* __restrict__ A1,
    const __hip_bfloat16* __restrict__ A2,
    const __hip_bfloat16* __restrict__ B0, const __hip_bfloat16* __restrict__ B1,
    const __hip_bfloat16* __restrict__ B2,
    float* __restrict__ P0, float* __restrict__ P1, float* __restrict__ P2, int K, int KC)
{
  __shared__ __bf16 As[2][128*32];
  __shared__ __bf16 Bs[2][128*32];
  const int zi = blockIdx.z;
  const __hip_bfloat16* Ah = (zi == 0) ? A0 : (zi == 1) ? A1 : A2;
  const __hip_bfloat16* Bh = (zi == 0) ? B0 : (zi == 1) ? B1 : B2;
  float* parts = (zi == 0) ? P0 : (zi == 1) ? P1 : P2;
  const int tid = threadIdx.x;
  const int bm = blockIdx.x*128;
  const int z = blockIdx.y;
  const int wid = tid >> 6, lane = tid & 63;
  const int wr = (wid >> 1)*64, wc = (wid & 1)*64;
  const int fr = lane & 15, kg = lane >> 4;
  const int srow = tid >> 2, sk = (tid & 3)*8;
  f32x4 acc[4][4] = {};
  const int kend = z*KC + KC;
#define SK3_STAGE(kt_, b_) do{ \
    gload_lds16b(Ah + (size_t)(bm+srow)*K + (kt_) + sk,    As[b_] + wid*512); \
    gload_lds16b(Ah + (size_t)(bm+srow+64)*K + (kt_) + sk, As[b_] + wid*512 + 64*32); \
    gload_lds16b(Bh + (size_t)(srow)*K + (kt_) + sk,       Bs[b_] + wid*512); \
    gload_lds16b(Bh + (size_t)(srow+64)*K + (kt_) + sk,    Bs[b_] + wid*512 + 64*32); \
  }while(0)
  SK3_STAGE(z*KC, 0);
  __builtin_amdgcn_s_waitcnt(0x3F70);
  __builtin_amdgcn_s_barrier();
  __builtin_amdgcn_sched_barrier(0);
  int buf = 0;
  for (int kt = z*KC; kt < kend; kt += 32){
    if (kt + 32 < kend) SK3_STAGE(kt+32, buf^1);
    bf16x8 af[4], bfr[4];
#pragma unroll
    for (int i = 0; i < 4; i++){
      af[i]  = *(const bf16x8*)(As[buf] + (wr + i*16 + fr)*32 + kg*8);
      bfr[i] = *(const bf16x8*)(Bs[buf] + (wc + i*16 + fr)*32 + kg*8);
    }
#pragma unroll
    for (int mi = 0; mi < 4; mi++)
#pragma unroll
      for (int ni = 0; ni < 4; ni++)
        acc[mi][ni] = __builtin_amdgcn_mfma_f32_16x16x32_bf16(af[mi], bfr[ni], acc[mi][ni], 0, 0, 0);
    __builtin_amdgcn_sched_barrier(0);
    __builtin_amdgcn_s_waitcnt(0x3F70);
    __builtin_amdgcn_s_barrier();
    __builtin_amdgcn_sched_barrier(0);
    buf ^= 1;
  }
#undef SK3_STAGE
  float* Cc = parts + (size_t)z*BT_*128;
  const int orow0 = bm + wr + kg*4;
  const int ocol0 = wc + fr;
#pragma unroll
  for (int mi = 0; mi < 4; mi++)
#pragma unroll
    for (int ni = 0; ni < 4; ni++)
#pragma unroll
      for (int j = 0; j < 4; j++)
        Cc[(size_t)(orow0 + mi*16 + j)*128 + ocol0 + ni*16] = acc[mi][ni][j];
}

// ---------------- batched reduce for 3 parts sets; z-specific tanh ranges ----------------
__global__ __launch_bounds__(256) void reduce_sk3(const float* __restrict__ P0, const float* __restrict__ P1,
                                                  const float* __restrict__ P2,
                                                  float* __restrict__ O0, float* __restrict__ O1,
                                                  float* __restrict__ O2){
  const int zi = blockIdx.y;
  const float* parts = (zi == 0) ? P0 : (zi == 1) ? P1 : P2;
  float* out = (zi == 0) ? O0 : (zi == 1) ? O1 : O2;
  const int hi = (zi == 0) ? 64 : (zi == 1) ? 128 : 16;   // wa1: 0..64, g1: all, k1: 0..16
  size_t idx = (size_t)blockIdx.x*256 + threadIdx.x;  // BT*128
  float s = 0.f;
#pragma unroll
  for (int z = 0; z < KS_; z++) s += parts[(size_t)z*BT_*128 + idx];
  int c = (int)(idx & 127);
  if (c < hi) s = tanhf(s);
  out[idx] = s;
}

// ---------------- reduce split-K parts + fused tanh on column range ----------------
__global__ __launch_bounds__(256) void reduce_sk(const float* __restrict__ parts, float* __restrict__ out,
                                                 int tanh_lo, int tanh_hi){
  size_t idx = (size_t)blockIdx.x*256 + threadIdx.x;  // BT*128
  float s = 0.f;
#pragma unroll
  for (int z = 0; z < KS_; z++) s += parts[(size_t)z*BT_*128 + idx];
  int c = (int)(idx & 127);
  if (c >= tanh_lo && c < tanh_hi) s = tanhf(s);
  out[idx] = s;
}

// ---------------- g = tanh'd g1[BT,128] @ gw2[128,C] -> bf16 ----------------
__global__ __launch_bounds__(256) void mm_sk_g(const float* __restrict__ A, const float* __restrict__ W,
                                               __hip_bfloat16* __restrict__ out, int K){
  const int j = blockIdx.y*256 + threadIdx.x;
  const int i0 = blockIdx.x*8;
  float acc[8] = {0,0,0,0,0,0,0,0};
  for (int k = 0; k < K; k++){
    float wv = W[(size_t)k*C_ + j];
#pragma unroll
    for (int r = 0; r < 8; r++) acc[r] += A[(size_t)(i0+r)*K + k] * wv;
  }
#pragma unroll
  for (int r = 0; r < 8; r++) out[(size_t)(i0+r)*C_ + j] = __float2bfloat16(acc[r]);
}

// ---------------- maa einsum + mix -> bf16 xrg/xwa/xk/xv ----------------
__global__ __launch_bounds__(256) void mix_kernel(
    const float* __restrict__ m1, const float* __restrict__ w2,
    const float* __restrict__ x, const float* __restrict__ xx,
    const float* __restrict__ maa_rg, const float* __restrict__ maa_wa,
    const float* __restrict__ maa_k, const float* __restrict__ maa_v,
    __hip_bfloat16* __restrict__ xrg_h, __hip_bfloat16* __restrict__ xwa_h,
    __hip_bfloat16* __restrict__ xk_h, __hip_bfloat16* __restrict__ xv_h)
{
  const int j = blockIdx.y*256 + threadIdx.x;
  const int i0 = blockIdx.x*8;
  float acc[4][8] = {};
#pragma unroll
  for (int f = 0; f < 4; f++){
    for (int d = 0; d < 32; d++){
      float wv = w2[((size_t)f*32 + d)*C_ + j];
#pragma unroll
      for (int r = 0; r < 8; r++)
        acc[f][r] += m1[(size_t)(i0+r)*128 + f*32 + d] * wv;
    }
  }
  float mrg_ = maa_rg[j], mwa_ = maa_wa[j], mk_ = maa_k[j], mv_ = maa_v[j];
#pragma unroll
  for (int r = 0; r < 8; r++){
    size_t idx = (size_t)(i0+r)*C_ + j;
    float xval = x[idx], xxv = xx[idx];
    xrg_h[idx] = __float2bfloat16(xval + xxv*(mrg_ + acc[0][r]));
    xwa_h[idx] = __float2bfloat16(xval + xxv*(mwa_ + acc[1][r]));
    xk_h[idx]  = __float2bfloat16(xval + xxv*(mk_  + acc[2][r]));
    xv_h[idx]  = __float2bfloat16(xval + xxv*(mv_  + acc[3][r]));
  }
}

// ---------------- bf16 MFMA GEMM: C[M,N] = A[M,K] * B[N,K]^T (fp32 out, btc layout) ----------------
// 2-phase double-buffered gload_lds pipeline
__global__ __launch_bounds__(256) void gemm_bt(const __hip_bfloat16* __restrict__ Ah,
                                               const __hip_bfloat16* __restrict__ Bh,
                                               float* __restrict__ Cc, int M, int Nn, int K){
  __shared__ __bf16 As[2][128*32];
  __shared__ __bf16 Bs[2][128*32];
  const int tid = threadIdx.x;
  const int bm = blockIdx.x*128, bn = blockIdx.y*128;
  const int wid = tid >> 6, lane = tid & 63;
  const int wr = (wid >> 1)*64, wc = (wid & 1)*64;
  const int fr = lane & 15, kg = lane >> 4;
  const int srow = tid >> 2, sk = (tid & 3)*8;
  f32x4 acc[4][4] = {};
#define BT_STAGE(kt_, b_) do{ \
    gload_lds16b(Ah + (size_t)(bm+srow)*K + (kt_) + sk,    As[b_] + wid*512); \
    gload_lds16b(Ah + (size_t)(bm+srow+64)*K + (kt_) + sk, As[b_] + wid*512 + 64*32); \
    gload_lds16b(Bh + (size_t)(bn+srow)*K + (kt_) + sk,    Bs[b_] + wid*512); \
    gload_lds16b(Bh + (size_t)(bn+srow+64)*K + (kt_) + sk, Bs[b_] + wid*512 + 64*32); \
  }while(0)
  BT_STAGE(0, 0);
  __builtin_amdgcn_s_waitcnt(0x3F70);
  __builtin_amdgcn_s_barrier();
  __builtin_amdgcn_sched_barrier(0);
  int buf = 0;
  for (int kt = 0; kt < K; kt += 32){
    if (kt + 32 < K) BT_STAGE(kt+32, buf^1);
    bf16x8 af[4], bfr[4];
#pragma unroll
    for (int i = 0; i < 4; i++){
      af[i]  = *(const bf16x8*)(As[buf] + (wr + i*16 + fr)*32 + kg*8);
      bfr[i] = *(const bf16x8*)(Bs[buf] + (wc + i*16 + fr)*32 + kg*8);
    }
#pragma unroll
    for (int mi = 0; mi < 4; mi++)
#pragma unroll
      for (int ni = 0; ni < 4; ni++)
        acc[mi][ni] = __builtin_amdgcn_mfma_f32_16x16x32_bf16(af[mi], bfr[ni], acc[mi][ni], 0, 0, 0);
    __builtin_amdgcn_sched_barrier(0);
    __builtin_amdgcn_s_waitcnt(0x3F70);
    __builtin_amdgcn_s_barrier();
    __builtin_amdgcn_sched_barrier(0);
    buf ^= 1;
  }
#undef BT_STAGE
  const int orow0 = bm + wr + kg*4;
  const int ocol0 = bn + wc + fr;
#pragma unroll
  for (int mi = 0; mi < 4; mi++)
#pragma unroll
    for (int ni = 0; ni < 4; ni++)
#pragma unroll
      for (int j = 0; j < 4; j++)
        Cc[(size_t)(orow0 + mi*16 + j)*Nn + ocol0 + ni*16] = acc[mi][ni][j];
}

// ---------------- batched r/k/v GEMM, C in [B,H,T,64] (bhtn) layout, grid.z selects triple ----------------
__global__ __launch_bounds__(256) void gemm_bt_T3(
    const __hip_bfloat16* __restrict__ A0, const __hip_bfloat16* __restrict__ A1,
    const __hip_bfloat16* __restrict__ A2,
    const __hip_bfloat16* __restrict__ B0, const __hip_bfloat16* __restrict__ B1,
    const __hip_bfloat16* __restrict__ B2,
    float* __restrict__ C0, float* __restrict__ C1, float* __restrict__ C2, int K)
{
  __shared__ __bf16 As[2][128*32];
  __shared__ __bf16 Bs[2][128*32];
  const int zi = blockIdx.z;
  const __hip_bfloat16* Ah = (zi == 0) ? A0 : (zi == 1) ? A1 : A2;
  const __hip_bfloat16* Bh = (zi == 0) ? B0 : (zi == 1) ? B1 : B2;
  float* Cc = (zi == 0) ? C0 : (zi == 1) ? C1 : C2;
  const int tid = threadIdx.x;
  const int bm = blockIdx.x*128, bn = blockIdx.y*128;
  const int wid = tid >> 6, lane = tid & 63;
  const int wr = (wid >> 1)*64, wc = (wid & 1)*64;
  const int fr = lane & 15, kg = lane >> 4;
  const int srow = tid >> 2, sk = (tid & 3)*8;
  f32x4 acc[4][4] = {};
#define T3_STAGE(kt_, b_) do{ \
    gload_lds16b(Ah + (size_t)(bm+srow)*K + (kt_) + sk,    As[b_] + wid*512); \
    gload_lds16b(Ah + (size_t)(bm+srow+64)*K + (kt_) + sk, As[b_] + wid*512 + 64*32); \
    gload_lds16b(Bh + (size_t)(bn+srow)*K + (kt_) + sk,    Bs[b_] + wid*512); \
    gload_lds16b(Bh + (size_t)(bn+srow+64)*K + (kt_) + sk, Bs[b_] + wid*512 + 64*32); \
  }while(0)
  T3_STAGE(0, 0);
  __builtin_amdgcn_s_waitcnt(0x3F70);
  __builtin_amdgcn_s_barrier();
  __builtin_amdgcn_sched_barrier(0);
  int buf = 0;
  for (int kt = 0; kt < K; kt += 32){
    if (kt + 32 < K) T3_STAGE(kt+32, buf^1);
    bf16x8 af[4], bfr[4];
#pragma unroll
    for (int i = 0; i < 4; i++){
      af[i]  = *(const bf16x8*)(As[buf] + (wr + i*16 + fr)*32 + kg*8);
      bfr[i] = *(const bf16x8*)(Bs[buf] + (wc + i*16 + fr)*32 + kg*8);
    }
#pragma unroll
    for (int mi = 0; mi < 4; mi++)
#pragma unroll
      for (int ni = 0; ni < 4; ni++)
        acc[mi][ni] = __builtin_amdgcn_mfma_f32_16x16x32_bf16(af[mi], bfr[ni], acc[mi][ni], 0, 0, 0);
    __builtin_amdgcn_sched_barrier(0);
    __builtin_amdgcn_s_waitcnt(0x3F70);
    __builtin_amdgcn_s_barrier();
    __builtin_amdgcn_sched_barrier(0);
    buf ^= 1;
  }
#undef T3_STAGE
  const int r0 = bm + wr + kg*4;
  const int c0 = bn + wc + fr;
#pragma unroll
  for (int mi = 0; mi < 4; mi++)
#pragma unroll
    for (int ni = 0; ni < 4; ni++)
#pragma unroll
      for (int j = 0; j < 4; j++)
        Cc[bhtn_idx(r0 + mi*16 + j, c0 + ni*16)] = acc[mi][ni][j];
}

// ---------------- fused LoRA stage-2 + decay/gates + kk-normalize + b=kk*a (writes bhtn) ----------------
// wa1[BT,128]: cols 0..63 = tanh(d1), 64..79 = a1, 80..95 = ma1
// k1c[BT,128]: cols 0..15 = tanh(kk1), 16..31 = mk1
// Wave = 64 consecutive channels = one head (j base 64-aligned) -> per-head L2 norm in-register.
__global__ __launch_bounds__(256) void lora2_kernel(
    const float* __restrict__ wa1, const float* __restrict__ k1c,
    const float* __restrict__ dw2, const float* __restrict__ aw2, const float* __restrict__ maw2,
    const float* __restrict__ mkw2, const float* __restrict__ kkw2,
    const float* __restrict__ td, const float* __restrict__ aaaaa,
    const float* __restrict__ misc_a, const float* __restrict__ misc_k,
    float* __restrict__ k0, float* __restrict__ b_out,
    float* __restrict__ ew_out, float* __restrict__ kk0_out)
{
  const int j = blockIdx.y*256 + threadIdx.x;
  const int i0 = blockIdx.x*8;
  float accW[8] = {}, accA[8] = {}, accMA[8] = {}, accMK[8] = {}, accKK[8] = {};
  for (int k = 0; k < 64; k++){
    float wv = dw2[(size_t)k*C_ + j];
#pragma unroll
    for (int r = 0; r < 8; r++) accW[r] += wa1[(size_t)(i0+r)*128 + k] * wv;
  }
  for (int k = 0; k < 16; k++){
    float w_a  = aw2[(size_t)k*C_ + j];
    float w_ma = maw2[(size_t)k*C_ + j];
    float w_mk = mkw2[(size_t)k*C_ + j];
    float w_kk = kkw2[(size_t)k*C_ + j];
#pragma unroll
    for (int r = 0; r < 8; r++){
      accA[r]  += wa1[(size_t)(i0+r)*128 + 64 + k] * w_a;
      accMA[r] += wa1[(size_t)(i0+r)*128 + 80 + k] * w_ma;
      accKK[r] += k1c[(size_t)(i0+r)*128 + k] * w_kk;
      accMK[r] += k1c[(size_t)(i0+r)*128 + 16 + k] * w_mk;
    }
  }
  float tdv = td[j], aav = aaaaa[j], mav = misc_a[j], mkv = misc_k[j];
#pragma unroll
  for (int r = 0; r < 8; r++){
    size_t idx = bhtn_idx(i0+r, j);
    float u  = tdv + accW[r];
    float w  = -log1pf(expf(-u)) - 0.5f;               // -softplus(-u) - 0.5
    float a  = 1.f/(1.f + expf(-(aav + accA[r])));
    float ma = 1.f/(1.f + expf(-(mav + accMA[r])));
    float mk = 1.f/(1.f + expf(-(mkv + accMK[r])));
    float kv = k0[idx];
    float kk = kv + accKK[r];
    // fused per-head normalize: this wave's 64 lanes ARE this head's 64 channels for row i0+r
    float ss  = wave64_sum(kk*kk);
    float kkn = kk / fmaxf(sqrtf(ss), 1e-12f);
    kk0_out[idx] = kkn;
    b_out[idx]   = kkn * a;
    float kn = kv * (ma + a*(1.f - ma)) * expf(fminf(w*mk, 0.f));
    k0[idx] = kn;
    ew_out[idx] = expf(w);
  }
}

// ---------------- RWKV-7 recurrence: 1024 blocks x 64 threads, direct global->reg, 8-slot ring ----------------
// Lane map: cf = lane>>4 (v-column 0..3), kq = lane&15 (k-group, 4 k's). Streams load directly
// global->regs. 8-slot prefetch ring (distance 7, 42 loads in flight) to cover the ~50%-HBM-miss
// latency (Little's law). Unroll-by-8 keeps slot indices compile-time (unroll-16 in R15 let the
// compiler compress the ring). Per-step kq==0 store (R14's proven form).
__global__ __launch_bounds__(64, 1) void rec_kernel(
    const float* __restrict__ rr, const float* __restrict__ kx,
    const float* __restrict__ vx, const float* __restrict__ ew,
    const float* __restrict__ kkv, const float* __restrict__ bsv,
    const float* __restrict__ s0, float* __restrict__ o, float* __restrict__ sT)
{
  const int g = blockIdx.x;            // 1024 = vg*64 + bh  (g%8==bh%8 -> XCD-local sharing)
  const int bh = g & 63;
  const int vg = g >> 6;               // 0..15
  const int b = bh >> 5, h = bh & 31;
  const int lane = threadIdx.x;
  const int cf = lane >> 4;            // v-column within block (DPP row id)
  const int kq = lane & 15;            // k-group (4 consecutive k)
  const int k0 = kq*4;
  const int v = vg*4 + cf;

  float S0, S1, S2, S3;
  {
    const float* p = s0 + ((size_t)bh*64 + k0)*64 + v;
    S0 = p[0]; S1 = p[64]; S2 = p[128]; S3 = p[192];
  }

  const size_t sb = (size_t)bh*T_*64;  // stream base (bhtn)
  const float* gA = kkv + sb + k0;     // a
  const float* gE = ew  + sb + k0;     // e
  const float* gK = kx  + sb + k0;     // k
  const float* gB = bsv + sb + k0;     // b
  const float* gR = rr  + sb + k0;     // r
  const float* gV = vx  + sb + v;      // v (per-lane column)
  float* ob = o + (size_t)b*T_*C_ + h*64 + v;   // + t*C_

  float4 Aq[8], Eq[8], Kq[8], Bq[8], Rq[8];
  float  Vq[8];

#define LOADT(t_, sl_) do{ \
    Aq[sl_] = *(const float4*)(gA + (size_t)(t_)*64); \
    Eq[sl_] = *(const float4*)(gE + (size_t)(t_)*64); \
    Kq[sl_] = *(const float4*)(gK + (size_t)(t_)*64); \
    Bq[sl_] = *(const float4*)(gB + (size_t)(t_)*64); \
    Rq[sl_] = *(const float4*)(gR + (size_t)(t_)*64); \
    Vq[sl_] = gV[(size_t)(t_)*64]; \
  }while(0)

  LOADT(0, 0); LOADT(1, 1); LOADT(2, 2); LOADT(3, 3);
  LOADT(4, 4); LOADT(5, 5); LOADT(6, 6);

  for (int tb = 0; tb < T_; tb += 8){
#pragma unroll
    for (int s = 0; s < 8; s++){
      const int t = tb + s;
      const int tn = (t + 7 < T_) ? (t + 7) : (T_ - 1);   // tail re-load is harmless
      LOADT(tn, (s + 7) & 7);
      const float4 A  = Aq[s];
      const float4 E  = Eq[s];
      const float4 Kk = Kq[s];
      const float4 Bv = Bq[s];
      const float4 R  = Rq[s];
      const float  vt = Vq[s];
      float p = (A.x*S0 + A.y*S1) + (A.z*S2 + A.w*S3);
      p = red16(p);                      // sa = -p (folded into the update)
      S0 = S0*E.x + Kk.x*vt - Bv.x*p;
      S1 = S1*E.y + Kk.y*vt - Bv.y*p;
      S2 = S2*E.z + Kk.z*vt - Bv.z*p;
      S3 = S3*E.w + Kk.w*vt - Bv.w*p;
      float op = (R.x*S0 + R.y*S1) + (R.z*S2 + R.w*S3);
      op = red16(op);
      if (kq == 0)                       // lanes 0,16,32,48 store (4 consecutive v)
        ob[(size_t)t*C_] = op;
    }
  }
#undef LOADT
  float* pT = sT + ((size_t)bh*64 + k0)*64 + v;
  pT[0] = S0; pT[64] = S1; pT[128] = S2; pT[192] = S3;
}

// ---------------- GroupNorm + faaaa term + *g -> z (bf16) ----------------
// o,g,z in btc layout; r,k,v in bhtn layout.
__global__ __launch_bounds__(256) void post_kernel(
    const float* __restrict__ o, const float* __restrict__ r, const float* __restrict__ k,
    const float* __restrict__ v, const __hip_bfloat16* __restrict__ g,
    const float* __restrict__ lnw, const float* __restrict__ lnb,
    const float* __restrict__ faaaa, __hip_bfloat16* __restrict__ z_h)
{
  const size_t grp = (size_t)blockIdx.x*4 + (threadIdx.x >> 6);  // bt*H + h
  const int lane = threadIdx.x & 63;
  const int h = (int)(grp & (H_-1));
  const int bt = (int)(grp >> 5);
  const size_t idx  = grp*64 + lane;                              // btc
  const size_t idx2 = (((size_t)(bt >> 10)*H_ + h)*T_ + (bt & 1023))*64 + lane;  // bhtn
  const int ci = h*64 + lane;
  float y = o[idx];
  float mu = wave64_sum(y) * (1.f/64.f);
  float d = y - mu;
  float var = wave64_sum(d*d) * (1.f/64.f);
  float yn = d * rsqrtf(var + 64e-5f) * lnw[ci] + lnb[ci];
  float s = wave64_sum(r[idx2]*k[idx2]*faaaa[ci]);
  float xo = yn + s*v[idx2];
  z_h[idx] = __float2bfloat16(xo * __bfloat162float(g[idx]));
}

extern "C" void kernel_launch(void* const* d_in, const int* in_sizes, int n_in,
                              void* d_out, int out_size, void* d_ws, size_t ws_size,
                              hipStream_t stream){
  (void)in_sizes; (void)n_in; (void)out_size;
  const float* x      = (const float*)d_in[0];
  const float* shift  = (const float*)d_in[1];
  const float* wkv0   = (const float*)d_in[2];
  const float* maa_x  = (const float*)d_in[3];
  const float* maa_rg = (const float*)d_in[4];
  const float* maa_wa = (const float*)d_in[5];
  const float* maa_k  = (const float*)d_in[6];
  const float* maa_v  = (const float*)d_in[7];
  const float* maa_w1 = (const float*)d_in[8];
  const float* maa_w2 = (const float*)d_in[9];
  const float* tdecay = (const float*)d_in[10];
  const float* dw1    = (const float*)d_in[11];
  const float* dw2    = (const float*)d_in[12];
  const float* faaaa  = (const float*)d_in[13];
  const float* aaaaa  = (const float*)d_in[14];
  const float* aw1    = (const float*)d_in[15];
  const float* aw2    = (const float*)d_in[16];
  const float* kkw1   = (const float*)d_in[17];
  const float* kkw2   = (const float*)d_in[18];
  const float* gw1    = (const float*)d_in[19];
  const float* gw2    = (const float*)d_in[20];
  const float* maw1   = (const float*)d_in[21];
  const float* maw2   = (const float*)d_in[22];
  const float* misc_a = (const float*)d_in[23];
  const float* mkw1   = (const float*)d_in[24];
  const float* mkw2   = (const float*)d_in[25];
  const float* misc_k = (const float*)d_in[26];
  const float* Wr     = (const float*)d_in[27];
  const float* Wk     = (const float*)d_in[28];
  const float* Wv     = (const float*)d_in[29];
  const float* Wo     = (const float*)d_in[30];
  const float* lnw    = (const float*)d_in[31];
  const float* lnb    = (const float*)d_in[32];

  float* out0 = (float*)d_out;                 // [B,T,C]  (also holds o pre-epilogue)
  float* out1 = out0 + BTC_;                   // [B,C]
  float* outS = out1 + (size_t)B_*C_;          // [B,H,N,N]

  const size_t NEEDED = (6*BTC_ + (size_t)3*BT_*128)*4 + 5*CC_*2 + (size_t)4*128*2048*2;
  if (ws_size < NEEDED) return;

  float* ws = (float*)d_ws;
  float* rbuf  = ws;            // bhtn
  float* kbuf  = ws + 1*BTC_;   // bhtn
  float* vbuf  = ws + 2*BTC_;   // bhtn
  float* abuf  = ws + 3*BTC_;   // b_s (bhtn); early alias: xx (btc)
  float* ewbuf = ws + 4*BTC_;   // exp(w) (bhtn); early alias: Wk_h
  float* kkbuf = ws + 5*BTC_;   // kk (bhtn);     early alias: Wv_h
  float* xx    = abuf;
  float* wa1   = ws + 6*BTC_;
  float* g1f   = wa1 + (size_t)BT_*128;
  float* k1c   = g1f + (size_t)BT_*128;
  float* parts = rbuf;
  float* m1f   = vbuf;
  __hip_bfloat16* hb = (__hip_bfloat16*)(k1c + (size_t)BT_*128);
  __hip_bfloat16* xrg_h = hb;
  __hip_bfloat16* xwa_h = hb + 1*CC_;
  __hip_bfloat16* xk_h  = hb + 2*CC_;
  __hip_bfloat16* xv_h  = hb + 3*CC_;
  __hip_bfloat16* Wb    = hb + 4*CC_;
  __hip_bfloat16* WtB   = hb + 5*CC_;
  __hip_bfloat16* Wt_m  = WtB;
  __hip_bfloat16* Wt_wa = WtB + (size_t)128*2048;
  __hip_bfloat16* Wt_g  = WtB + (size_t)2*128*2048;
  __hip_bfloat16* Wt_k  = WtB + (size_t)3*128*2048;
  __hip_bfloat16* xmx_h = xv_h;
  __hip_bfloat16* g_h   = xwa_h;
  __hip_bfloat16* z_h   = xv_h;
  __hip_bfloat16* Wk_h  = (__hip_bfloat16*)ewbuf;
  __hip_bfloat16* Wv_h  = (__hip_bfloat16*)kkbuf;

  dim3 blk(256);
  const int KC = C_/KS_;

  hipMemsetAsync(WtB, 0, (size_t)4*128*2048*2, stream);
  tp_pack7<<<dim3(64, 14), blk, 0, stream>>>(maa_w1, dw1, aw1, maw1, gw1, kkw1, mkw1, WtB);

  shift_kernel<<<(int)(BTC_/256), blk, 0, stream>>>(x, shift, maa_x, xx, xmx_h, out1);

  gemm_sk<<<dim3(BT_/128, KS_), blk, 0, stream>>>(xmx_h, Wt_m, parts, C_, KC);
  reduce_sk<<<BT_*128/256, blk, 0, stream>>>(parts, m1f, 0, 128);

  mix_kernel<<<dim3(BT_/8, C_/256), blk, 0, stream>>>(m1f, maa_w2, x, xx, maa_rg, maa_wa, maa_k, maa_v,
                                                      xrg_h, xwa_h, xk_h, xv_h);

  // 3 independent skinny GEMMs batched: (xwa,Wt_wa)->P0(rbuf), (xrg,Wt_g)->P1(kbuf), (xk,Wt_k)->P2(vbuf)
  gemm_sk3<<<dim3(BT_/128, KS_, 3), blk, 0, stream>>>(xwa_h, xrg_h, xk_h,
                                                      Wt_wa, Wt_g, Wt_k,
                                                      rbuf, kbuf, vbuf, C_, KC);
  reduce_sk3<<<dim3(BT_*128/256, 3), blk, 0, stream>>>(rbuf, kbuf, vbuf, wa1, g1f, k1c);

  mm_sk_g<<<dim3(BT_/8, C_/256), blk, 0, stream>>>(g1f, gw2, g_h, 128);

  f2bf3_kernel<<<dim3((int)(CC_/256), 3), blk, 0, stream>>>(Wr, Wk, Wv, Wb, Wk_h, Wv_h);
  gemm_bt_T3<<<dim3(BT_/128, C_/128, 3), blk, 0, stream>>>(xrg_h, xk_h, xv_h,
                                                           Wb, Wk_h, Wv_h,
                                                           rbuf, kbuf, vbuf, C_);

  lora2_kernel<<<dim3(BT_/8, C_/256), blk, 0, stream>>>(wa1, k1c,
                                                        dw2, aw2, maw2, mkw2, kkw2,
                                                        tdecay, aaaaa, misc_a, misc_k,
                                                        kbuf, abuf, ewbuf, kkbuf);

  rec_kernel<<<1024, dim3(64), 0, stream>>>(rbuf, kbuf, vbuf, ewbuf, kkbuf, abuf, wkv0, out0, outS);

  post_kernel<<<BT_*H_/4, blk, 0, stream>>>(out0, rbuf, kbuf, vbuf, g_h, lnw, lnb, faaaa, z_h);
  f2bf_kernel<<<(int)(CC_/256), blk, 0, stream>>>(Wo, Wb, CC_);
  gemm_bt<<<dim3(BT_/128, C_/128), blk, 0, stream>>>(z_h, Wb, out0, BT_, C_, C_);
}